// Round 20
// baseline (450.093 us; speedup 1.0000x reference)
//
#include <hip/hip_runtime.h>
#include <math.h>

#define EPSF 1e-5f

typedef __attribute__((ext_vector_type(8))) _Float16 h16x8;
typedef __attribute__((ext_vector_type(4))) float f32x4;
typedef __attribute__((ext_vector_type(4))) unsigned short us4;
typedef __attribute__((ext_vector_type(8))) unsigned short us8;

static __device__ __forceinline__ unsigned short f2h(float f) {
  _Float16 h = (_Float16)f;
  return __builtin_bit_cast(unsigned short, h);
}
static __device__ __forceinline__ float h2f(unsigned short u) {
  _Float16 h = __builtin_bit_cast(_Float16, u);
  return (float)h;
}
static __device__ __forceinline__ int ibcast(int v, int l) {  // uniform l only
  return __builtin_amdgcn_readlane(v, l);
}
static __device__ __forceinline__ int lanegather(int v, int srcLane) {
  return __builtin_amdgcn_ds_bpermute(srcLane << 2, v);
}

// ---------------- merged: histogram(+rank) + weight prep ---------------------
// blocks [0, degBlocks): deg/rank atomics; blocks [degBlocks, ...): fp16 prep.
// wsdt: [128][64] f16: c<64 -> Ws^T col c, c>=64 -> Wd^T col c-64 (k-major)
// wt2 : [192][320] f16 col-major-K (see kC_post1)
// wt3 : [64][64] f16 of W2^T (k-major per col)

__global__ __launch_bounds__(256) void k_front(
    const int* __restrict__ dst, int* __restrict__ deg, int* __restrict__ rank,
    int E, int degBlocks, const float* __restrict__ pre_W,
    const float* __restrict__ post_W1, const float* __restrict__ post_W2,
    unsigned short* __restrict__ wsdt, unsigned short* __restrict__ wt2,
    unsigned short* __restrict__ wt3) {
  int b = blockIdx.x;
  if (b < degBlocks) {
    int i = b * 256 + threadIdx.x;
    if (i < E) rank[i] = atomicAdd(&deg[dst[i]], 1);
    return;
  }
  int idx = (b - degBlocks) * 256 + threadIdx.x;
  if (idx < 128 * 64) {
    int c = idx >> 6, k = idx & 63;
    float v = (c < 64) ? pre_W[k * 64 + c] : pre_W[(64 + k) * 64 + (c - 64)];
    wsdt[idx] = f2h(v);
  }
  int j = idx - 128 * 64;
  if (j >= 0 && j < 192 * 320) {
    int c = j / 320, k = j - c * 320;
    float v;
    if (c < 64) v = post_W1[k * 64 + c];
    else if (c < 128) v = (k < 64) ? 0.f : post_W1[(256 + k) * 64 + (c - 64)];
    else v = (k < 64) ? 0.f : post_W1[(512 + k) * 64 + (c - 128)];
    wt2[j] = f2h(v);
  }
  int m = idx - 128 * 64 - 192 * 320;
  if (m >= 0 && m < 64 * 64) {
    int c = m >> 6, k = m & 63;
    wt3[m] = f2h(post_W2[k * 64 + c]);
  }
}

__global__ __launch_bounds__(1024) void k_scan_a(const int* __restrict__ deg,
                                                 int* __restrict__ offs,
                                                 int* __restrict__ bsum,
                                                 float* __restrict__ aux2, int N) {
  __shared__ int s[1024];
  int t = threadIdx.x;
  int i = blockIdx.x * 1024 + t;
  int v = (i < N) ? deg[i] : 0;
  s[t] = v;
  __syncthreads();
  for (int off = 1; off < 1024; off <<= 1) {
    int x = (t >= off) ? s[t - off] : 0;
    __syncthreads();
    s[t] += x;
    __syncthreads();
  }
  if (i < N) {
    offs[i] = s[t] - v;
    float logD = logf((float)v + 1.f);
    aux2[i * 2] = logD;                                         // amp scaler
    aux2[i * 2 + 1] = (v > 0) ? 1.f / fmaxf(logD, EPSF) : 0.f;  // att scaler
  }
  if (t == 1023) bsum[blockIdx.x] = s[1023];
}

__global__ __launch_bounds__(1024) void k_scan_b(int* __restrict__ bsum, int nb) {
  __shared__ int s[1024];
  int t = threadIdx.x;
  int v = (t < nb) ? bsum[t] : 0;
  s[t] = v;
  __syncthreads();
  for (int off = 1; off < 1024; off <<= 1) {
    int x = (t >= off) ? s[t - off] : 0;
    __syncthreads();
    s[t] += x;
    __syncthreads();
  }
  if (t < nb) bsum[t] = s[t] - v;
}

__global__ __launch_bounds__(1024) void k_scan_c(int* __restrict__ offs,
                                                 const int* __restrict__ bsum,
                                                 int N) {
  int i = blockIdx.x * 1024 + threadIdx.x;
  if (i < N) offs[i] += bsum[blockIdx.x];
}

// ---------------- node projections: P_s = nf@Ws, P_d = nf@Wd + b (MFMA f16) --

__global__ __launch_bounds__(256) void kB_proj(
    const float* __restrict__ nf, const unsigned short* __restrict__ wsdt,
    const float* __restrict__ pre_b, unsigned short* __restrict__ ps,
    unsigned short* __restrict__ pd, int N) {
  __shared__ unsigned short at[64][72];
  int tid = threadIdx.x;
  int n0 = blockIdx.x * 64;
  for (int idx = tid; idx < 64 * 16; idx += 256) {
    int row = idx >> 4, s4 = idx & 15;
    int n = n0 + row;
    us4 o = {0, 0, 0, 0};
    if (n < N) {
      f32x4 v = *(const f32x4*)(nf + (long)n * 64 + s4 * 4);
      o.x = f2h(v.x); o.y = f2h(v.y); o.z = f2h(v.z); o.w = f2h(v.w);
    }
    *(us4*)&at[row][s4 * 4] = o;
    if (s4 < 2) { us4 z = {0, 0, 0, 0}; *(us4*)&at[row][64 + s4 * 4] = z; }
  }
  __syncthreads();
  int lane = tid & 63, w = tid >> 6;
  int r0 = w * 16;
  const unsigned short* ap = &at[r0 + (lane & 15)][(lane >> 4) * 8];
  const unsigned short* bp = wsdt + (lane & 15) * 64 + (lane >> 4) * 8;
  f32x4 acc[8];
#pragma unroll
  for (int c = 0; c < 8; c++) acc[c] = (f32x4){0.f, 0.f, 0.f, 0.f};
#pragma unroll
  for (int c = 0; c < 8; c++) {
#pragma unroll
    for (int kk = 0; kk < 2; kk++) {
      h16x8 a = *(const h16x8*)(ap + kk * 32);
      h16x8 b = *(const h16x8*)(bp + c * 1024 + kk * 32);
      acc[c] = __builtin_amdgcn_mfma_f32_16x16x32_f16(a, b, acc[c], 0, 0, 0);
    }
  }
  int rb = r0 + ((lane >> 4) << 2);
#pragma unroll
  for (int c = 0; c < 8; c++) {
    int col = c * 16 + (lane & 15);
    int cc = col & 63;
    float bv = (col >= 64) ? pre_b[cc] : 0.f;
#pragma unroll
    for (int r = 0; r < 4; r++) {
      int n = n0 + rb + r;
      if (n < N) {
        unsigned short val = f2h(acc[c][r] + bv);
        if (col >= 64) pd[(long)n * 64 + cc] = val;
        else ps[(long)n * 64 + cc] = val;
      }
    }
  }
}

// ---------------- phase 1a: partial = q + ps[src], scatter to CSR ------------
// Software-pipelined: group g+1's index/efeat loads issued during group g's
// epilogue; ps gathers pre-issued before the MFMA section.

__global__ __launch_bounds__(256) void kQe(
    const float* __restrict__ efeat, const float* __restrict__ pre_W,
    const unsigned short* __restrict__ ps,
    const int* __restrict__ src, const int* __restrict__ dst,
    const int* __restrict__ rank, const int* __restrict__ offs,
    unsigned short* __restrict__ rbuf, int E) {
  __shared__ unsigned short vt[4][16][72];
  int lane = threadIdx.x & 63, w = threadIdx.x >> 6;
  int colb = lane & 15, kg = lane >> 4;

  h16x8 bfrag[4];
#pragma unroll
  for (int ct = 0; ct < 4; ct++) {
    _Float16 tmp[8];
#pragma unroll
    for (int j = 0; j < 8; j++) {
      int k = kg * 8 + j;
      tmp[j] = (k < 16) ? (_Float16)pre_W[(128 + k) * 64 + ct * 16 + colb]
                        : (_Float16)0.f;
    }
    bfrag[ct] = *(h16x8*)tmp;
  }

  const int GROUPS = 4;
  long pbase = ((long)blockIdx.x * 4 + w) * (16 * GROUPS);
  if (pbase >= E) return;

  // loader for group g: indices + A fragment
  auto loadGroup = [&](int g, int& sv, int& posv, h16x8& afrag) {
    long p0 = pbase + (long)g * 16;
    long pl = p0 + colb;
    sv = 0; posv = 0;
    if (pl < E) {
      sv = __builtin_nontemporal_load(src + pl);
      int dv = __builtin_nontemporal_load(dst + pl);
      posv = offs[dv] + __builtin_nontemporal_load(rank + pl);
    }
    _Float16 tmp[8] = {0, 0, 0, 0, 0, 0, 0, 0};
    if (kg < 2 && pl < E) {
      f32x4 v0 = __builtin_nontemporal_load(
          (const f32x4*)(efeat + pl * 16 + kg * 8));
      f32x4 v1 = __builtin_nontemporal_load(
          (const f32x4*)(efeat + pl * 16 + kg * 8 + 4));
      tmp[0] = (_Float16)v0.x; tmp[1] = (_Float16)v0.y;
      tmp[2] = (_Float16)v0.z; tmp[3] = (_Float16)v0.w;
      tmp[4] = (_Float16)v1.x; tmp[5] = (_Float16)v1.y;
      tmp[6] = (_Float16)v1.z; tmp[7] = (_Float16)v1.w;
    }
    afrag = *(h16x8*)tmp;
  };

  int svC, posvC;
  h16x8 afragC;
  loadGroup(0, svC, posvC, afragC);

#pragma unroll 1
  for (int g = 0; g < GROUPS; g++) {
    long p0 = pbase + (long)g * 16;
    if (p0 >= E) return;

    // pre-issue all 16 ps gathers for current group (lane = channel)
    unsigned short psv[16];
#pragma unroll
    for (int i = 0; i < 16; i++) {
      int s_i = ibcast(svC, i);
      psv[i] = ps[(long)s_i * 64 + lane];
    }

    // prefetch next group's indices + A fragment (overlaps epilogue below)
    int svN = 0, posvN = 0;
    h16x8 afragN;
    bool hasNext = (g + 1 < GROUPS) && (p0 + 16 < E);
    if (hasNext) loadGroup(g + 1, svN, posvN, afragN);

    f32x4 acc[4];
#pragma unroll
    for (int ct = 0; ct < 4; ct++) acc[ct] = (f32x4){0.f, 0.f, 0.f, 0.f};
#pragma unroll
    for (int ct = 0; ct < 4; ct++)
      acc[ct] = __builtin_amdgcn_mfma_f32_16x16x32_f16(afragC, bfrag[ct],
                                                       acc[ct], 0, 0, 0);

    // stage q (fp16) into vt: row = kg*4+r, col = ct*16+colb
#pragma unroll
    for (int ct = 0; ct < 4; ct++)
#pragma unroll
      for (int r = 0; r < 4; r++)
        vt[w][kg * 4 + r][ct * 16 + colb] = f2h(acc[ct][r]);

    // partial = q + ps[src] back into vt, lane = channel
#pragma unroll
    for (int i = 0; i < 16; i++) {
      long p = p0 + i;
      if (p >= E) break;
      float v = h2f(vt[w][i][lane]) + h2f(psv[i]);
      vt[w][i][lane] = f2h(v);
    }

    // vectorized scatter: 2 wave-stores, each covers 8 rows x 128B.
#pragma unroll
    for (int pass = 0; pass < 2; pass++) {
      int row = pass * 8 + (lane >> 3);
      long p = p0 + row;
      long pos = (long)lanegather(posvC, row);
      if (p < E) {
        us8 val = *(const us8*)&vt[w][row][(lane & 7) * 8];
        *(us8*)(rbuf + pos * 64 + (lane & 7) * 8) = val;
      }
    }

    svC = svN;
    posvC = posvN;
    afragC = afragN;
  }
}

// ---------------- phase 1b: sequential segmented stats (+pd, +relu) ----------

__global__ __launch_bounds__(256) void kAgg(
    const unsigned short* __restrict__ rbuf, const unsigned short* __restrict__ pd,
    const int* __restrict__ offs, const int* __restrict__ deg,
    unsigned short* __restrict__ aggb, int N) {
  int lane = threadIdx.x & 63;
  int n = blockIdx.x * 4 + (threadIdx.x >> 6);
  if (n >= N) return;
  int dc = deg[n];
  long ab = (long)n * 256 + lane;
  if (dc == 0) {
    aggb[ab] = 0; aggb[ab + 64] = 0; aggb[ab + 128] = 0; aggb[ab + 192] = 0;
    return;
  }
  float pdv = h2f(pd[(long)n * 64 + lane]);
  long p = offs[n], pe = p + dc;
  float sa = 0.f, qa = 0.f, mx = 0.f, mn = 3.4e38f;
  for (; p + 4 <= pe; p += 4) {
    float v0 = fmaxf(h2f(rbuf[p * 64 + lane]) + pdv, 0.f);
    float v1 = fmaxf(h2f(rbuf[(p + 1) * 64 + lane]) + pdv, 0.f);
    float v2 = fmaxf(h2f(rbuf[(p + 2) * 64 + lane]) + pdv, 0.f);
    float v3 = fmaxf(h2f(rbuf[(p + 3) * 64 + lane]) + pdv, 0.f);
    sa += (v0 + v1) + (v2 + v3);
    qa = fmaf(v0, v0, qa); qa = fmaf(v1, v1, qa);
    qa = fmaf(v2, v2, qa); qa = fmaf(v3, v3, qa);
    mx = fmaxf(mx, fmaxf(fmaxf(v0, v1), fmaxf(v2, v3)));
    mn = fminf(mn, fminf(fminf(v0, v1), fminf(v2, v3)));
  }
  for (; p < pe; p++) {
    float v0 = fmaxf(h2f(rbuf[p * 64 + lane]) + pdv, 0.f);
    sa += v0;
    qa = fmaf(v0, v0, qa);
    mx = fmaxf(mx, v0);
    mn = fminf(mn, v0);
  }
  float invd = 1.f / (float)dc;
  float mean = sa * invd;
  float var = fmaxf(qa * invd - mean * mean, 0.f);
  float stdv = sqrtf(var + EPSF);
  aggb[ab] = f2h(mean);
  aggb[ab + 64] = f2h(mx);
  aggb[ab + 128] = f2h(mn);
  aggb[ab + 192] = f2h(stdv);
}

// ---------------- phase 2: post1 GEMM, K=320, B register-resident ------------

__global__ __launch_bounds__(256) void kC_post1(
    const float* __restrict__ nf, const unsigned short* __restrict__ aggb,
    const float* __restrict__ aux2, const unsigned short* __restrict__ wt2,
    const float* __restrict__ b1, unsigned short* __restrict__ x1,
    float* __restrict__ bn_sum, float* __restrict__ bn_ssq, int N) {
  __shared__ unsigned short At[64][328];  // 41 KB; reused as float[64][68] later
  int tid = threadIdx.x;
  int n0 = blockIdx.x * 64;
  int lane = tid & 63, w = tid >> 6;
  int colb = lane & 15, kg = lane >> 4;

  const unsigned short* bp0 = wt2 + (long)(w * 16 + colb) * 320 + kg * 8;
  const unsigned short* bp1 = wt2 + (long)(64 + w * 16 + colb) * 320 + kg * 8;
  const unsigned short* bp2 = wt2 + (long)(128 + w * 16 + colb) * 320 + kg * 8;
  h16x8 bf0[10], bf1[8], bf2[8];
#pragma unroll
  for (int kk = 0; kk < 10; kk++) bf0[kk] = *(const h16x8*)(bp0 + kk * 32);
#pragma unroll
  for (int j = 0; j < 8; j++) bf1[j] = *(const h16x8*)(bp1 + (j + 2) * 32);
#pragma unroll
  for (int j = 0; j < 8; j++) bf2[j] = *(const h16x8*)(bp2 + (j + 2) * 32);

  for (int idx = tid; idx < 64 * 40; idx += 256) {
    int row = idx / 40, s = idx - row * 40;
    int n = n0 + row;
    us8 o = {0, 0, 0, 0, 0, 0, 0, 0};
    if (n < N) {
      if (s < 8) {
        f32x4 v0 = *(const f32x4*)(nf + (long)n * 64 + s * 8);
        f32x4 v1 = *(const f32x4*)(nf + (long)n * 64 + s * 8 + 4);
        o[0] = f2h(v0.x); o[1] = f2h(v0.y); o[2] = f2h(v0.z); o[3] = f2h(v0.w);
        o[4] = f2h(v1.x); o[5] = f2h(v1.y); o[6] = f2h(v1.z); o[7] = f2h(v1.w);
      } else {
        o = *((const us8*)(aggb + (long)n * 256) + (s - 8));
      }
    }
    *(us8*)&At[row][s * 8] = o;
  }
  __syncthreads();

  f32x4 acc0[4], acc1[4], acc2[4];
#pragma unroll
  for (int s = 0; s < 4; s++) {
    acc0[s] = (f32x4){0.f, 0.f, 0.f, 0.f};
    acc1[s] = (f32x4){0.f, 0.f, 0.f, 0.f};
    acc2[s] = (f32x4){0.f, 0.f, 0.f, 0.f};
  }
#pragma unroll
  for (int s = 0; s < 4; s++) {
    const unsigned short* ap = &At[s * 16 + colb][kg * 8];
#pragma unroll
    for (int kk = 0; kk < 10; kk++) {
      h16x8 a = *(const h16x8*)(ap + kk * 32);
      acc0[s] = __builtin_amdgcn_mfma_f32_16x16x32_f16(a, bf0[kk], acc0[s], 0, 0, 0);
      if (kk >= 2) {
        acc1[s] = __builtin_amdgcn_mfma_f32_16x16x32_f16(a, bf1[kk - 2], acc1[s], 0, 0, 0);
        acc2[s] = __builtin_amdgcn_mfma_f32_16x16x32_f16(a, bf2[kk - 2], acc2[s], 0, 0, 0);
      }
    }
  }
  __syncthreads();

  float* sx = (float*)&At[0][0];
  int col = w * 16 + colb;
  float bv = b1[col];
#pragma unroll
  for (int s = 0; s < 4; s++) {
    int rb = s * 16 + kg * 4;
#pragma unroll
    for (int r = 0; r < 4; r++) {
      int n = n0 + rb + r;
      float x = 0.f;
      if (n < N) {
        float lg = aux2[(long)n * 2];
        float atf = aux2[(long)n * 2 + 1];
        x = fmaxf(acc0[s][r] + lg * acc1[s][r] + atf * acc2[s][r] + bv, 0.f);
      }
      sx[(rb + r) * 68 + col] = x;
    }
  }
  __syncthreads();

  for (int idx = tid; idx < 64 * 16; idx += 256) {
    int row = idx >> 4, s4 = idx & 15;
    int n = n0 + row;
    if (n < N) {
      const float* p = sx + row * 68 + s4 * 4;
      us4 o;
      o.x = f2h(p[0]); o.y = f2h(p[1]); o.z = f2h(p[2]); o.w = f2h(p[3]);
      *(us4*)(x1 + (long)n * 64 + s4 * 4) = o;
    }
  }
  if (tid < 64) {
    float s = 0.f, s2 = 0.f;
    for (int r = 0; r < 64; r++) {
      float v = sx[r * 68 + tid];
      s += v;
      s2 = fmaf(v, v, s2);
    }
    atomicAdd(&bn_sum[tid], s);
    atomicAdd(&bn_ssq[tid], s2);
  }
}

// ---------------- BN stats finalize -----------------------------------------

__global__ __launch_bounds__(64) void k_bnstat(
    const float* __restrict__ bn_sum, const float* __restrict__ bn_ssq,
    const float* __restrict__ gamma, const float* __restrict__ beta,
    float* __restrict__ scale, float* __restrict__ shift, float invN) {
  int j = threadIdx.x;
  float mu = bn_sum[j] * invN;
  float v = fmaxf(bn_ssq[j] * invN - mu * mu, 0.f);
  float sc = gamma[j] / sqrtf(v + EPSF);
  scale[j] = sc;
  shift[j] = beta[j] - mu * sc;
}

// ---------------- out = relu(BN(x1)@W2 + b2) + h_in (MFMA tile) --------------

__global__ __launch_bounds__(256) void k_post2(
    const unsigned short* __restrict__ x1, const unsigned short* __restrict__ wt3,
    const float* __restrict__ post_b2, const float* __restrict__ scale,
    const float* __restrict__ shift, const float* __restrict__ nf,
    float* __restrict__ out, int N) {
  __shared__ unsigned short at[64][72];
  int tid = threadIdx.x;
  int n0 = blockIdx.x * 64;
  for (int idx = tid; idx < 64 * 16; idx += 256) {
    int row = idx >> 4, s4 = idx & 15;
    int n = n0 + row;
    us4 o = {0, 0, 0, 0};
    if (n < N) {
      us4 xv = *(const us4*)(x1 + (long)n * 64 + s4 * 4);
      f32x4 sc = *(const f32x4*)(scale + s4 * 4);
      f32x4 sh = *(const f32x4*)(shift + s4 * 4);
      o.x = f2h(fmaf(h2f(xv.x), sc.x, sh.x));
      o.y = f2h(fmaf(h2f(xv.y), sc.y, sh.y));
      o.z = f2h(fmaf(h2f(xv.z), sc.z, sh.z));
      o.w = f2h(fmaf(h2f(xv.w), sc.w, sh.w));
    }
    *(us4*)&at[row][s4 * 4] = o;
  }
  __syncthreads();
  int lane = tid & 63, w = tid >> 6;
  int colb = lane & 15, kg = lane >> 4;
  int r0 = w * 16;
  const unsigned short* ap = &at[r0 + colb][kg * 8];
  const unsigned short* bp = wt3 + colb * 64 + kg * 8;
  f32x4 acc[4];
#pragma unroll
  for (int ct = 0; ct < 4; ct++) acc[ct] = (f32x4){0.f, 0.f, 0.f, 0.f};
#pragma unroll
  for (int kk = 0; kk < 2; kk++) {
    h16x8 a = *(const h16x8*)(ap + kk * 32);
#pragma unroll
    for (int ct = 0; ct < 4; ct++) {
      h16x8 b = *(const h16x8*)(bp + ct * (16 * 64) + kk * 32);
      acc[ct] = __builtin_amdgcn_mfma_f32_16x16x32_f16(a, b, acc[ct], 0, 0, 0);
    }
  }
  int rb = r0 + kg * 4;
#pragma unroll
  for (int ct = 0; ct < 4; ct++) {
    int col = ct * 16 + colb;
    float bv = post_b2[col];
#pragma unroll
    for (int r = 0; r < 4; r++) {
      int n = n0 + rb + r;
      if (n < N)
        out[(long)n * 64 + col] =
            fmaxf(acc[ct][r] + bv, 0.f) + nf[(long)n * 64 + col];
    }
  }
}

// ----------------------------------------------------------------------------

extern "C" void kernel_launch(void* const* d_in, const int* in_sizes, int n_in,
                              void* d_out, int out_size, void* d_ws, size_t ws_size,
                              hipStream_t stream) {
  const float* node_feat = (const float*)d_in[0];
  const float* edge_feat = (const float*)d_in[1];
  const float* pre_W = (const float*)d_in[2];
  const float* pre_b = (const float*)d_in[3];
  const float* post_W1 = (const float*)d_in[4];
  const float* post_b1 = (const float*)d_in[5];
  const float* bn_gamma = (const float*)d_in[6];
  const float* bn_beta = (const float*)d_in[7];
  const float* post_W2 = (const float*)d_in[8];
  const float* post_b2 = (const float*)d_in[9];
  const int* src = (const int*)d_in[10];
  const int* dst = (const int*)d_in[11];
  float* out = (float*)d_out;

  int N = in_sizes[0] / 64;
  int E = in_sizes[10];

  char* ws = (char*)d_ws;
  size_t off = 0;
  auto alloc = [&](size_t bytes) -> void* {
    void* p = ws + off;
    off += (bytes + 255) & ~(size_t)255;
    return p;
  };
  // deg/bn_sum/bn_ssq first + contiguous -> one memsetAsync zeroes them
  int* deg = (int*)alloc((size_t)N * 4);
  float* bn_sum = (float*)alloc(64 * 4);
  float* bn_ssq = (float*)alloc(64 * 4);
  size_t zero_span = off;
  int* offs = (int*)alloc((size_t)N * 4);
  int* rank = (int*)alloc((size_t)E * 4);
  int* bsum = (int*)alloc(1024 * 4);
  unsigned short* aggb = (unsigned short*)alloc((size_t)N * 256 * 2);
  float* aux2 = (float*)alloc((size_t)N * 2 * 4);
  unsigned short* psb = (unsigned short*)alloc((size_t)N * 64 * 2);
  unsigned short* pdb = (unsigned short*)alloc((size_t)N * 64 * 2);
  unsigned short* x1 = (unsigned short*)alloc((size_t)N * 64 * 2);
  unsigned short* wsdt = (unsigned short*)alloc(128 * 64 * 2);
  unsigned short* wt2 = (unsigned short*)alloc(192 * 320 * 2);
  unsigned short* wt3 = (unsigned short*)alloc(64 * 64 * 2);
  float* bn_scale = (float*)alloc(64 * 4);
  float* bn_shift = (float*)alloc(64 * 4);
  unsigned short* rbuf = (unsigned short*)alloc((size_t)E * 64 * 2);
  if (off > ws_size) return;  // fail loudly (output stays poisoned)

  int nscan = (N + 1023) / 1024;
  int degBlocks = (E + 255) / 256;
  int prepBlocks = (128 * 64 + 192 * 320 + 64 * 64 + 255) / 256;

  hipMemsetAsync(deg, 0, zero_span, stream);
  k_front<<<degBlocks + prepBlocks, 256, 0, stream>>>(
      dst, deg, rank, E, degBlocks, pre_W, post_W1, post_W2, wsdt, wt2, wt3);
  k_scan_a<<<nscan, 1024, 0, stream>>>(deg, offs, bsum, aux2, N);
  k_scan_b<<<1, 1024, 0, stream>>>(bsum, nscan);
  k_scan_c<<<nscan, 1024, 0, stream>>>(offs, bsum, N);
  kB_proj<<<(N + 63) / 64, 256, 0, stream>>>(node_feat, wsdt, pre_b, psb, pdb, N);

  kQe<<<(E + 255) / 256, 256, 0, stream>>>(edge_feat, pre_W, psb, src, dst,
                                           rank, offs, rbuf, E);
  kAgg<<<(N + 3) / 4, 256, 0, stream>>>(rbuf, pdb, offs, deg, aggb, N);

  kC_post1<<<(N + 63) / 64, 256, 0, stream>>>(node_feat, aggb, aux2, wt2,
                                              post_b1, x1, bn_sum, bn_ssq, N);

  k_bnstat<<<1, 64, 0, stream>>>(bn_sum, bn_ssq, bn_gamma, bn_beta, bn_scale,
                                 bn_shift, 1.0f / (float)N);

  k_post2<<<(N + 63) / 64, 256, 0, stream>>>(x1, wt3, post_b2, bn_scale,
                                             bn_shift, node_feat, out, N);
}

// Round 21
// 431.987 us; speedup vs baseline: 1.0419x; 1.0419x over previous
//
#include <hip/hip_runtime.h>
#include <math.h>

#define EPSF 1e-5f

typedef __attribute__((ext_vector_type(8))) _Float16 h16x8;
typedef __attribute__((ext_vector_type(4))) float f32x4;
typedef __attribute__((ext_vector_type(4))) unsigned short us4;
typedef __attribute__((ext_vector_type(8))) unsigned short us8;

static __device__ __forceinline__ unsigned short f2h(float f) {
  _Float16 h = (_Float16)f;
  return __builtin_bit_cast(unsigned short, h);
}
static __device__ __forceinline__ float h2f(unsigned short u) {
  _Float16 h = __builtin_bit_cast(_Float16, u);
  return (float)h;
}
static __device__ __forceinline__ int ibcast(int v, int l) {  // uniform l only
  return __builtin_amdgcn_readlane(v, l);
}
static __device__ __forceinline__ int lanegather(int v, int srcLane) {
  return __builtin_amdgcn_ds_bpermute(srcLane << 2, v);
}

// ---------------- merged: histogram(+rank) + weight prep ---------------------

__global__ __launch_bounds__(256) void k_front(
    const int* __restrict__ dst, int* __restrict__ deg, int* __restrict__ rank,
    int E, int degBlocks, const float* __restrict__ pre_W,
    const float* __restrict__ post_W1, const float* __restrict__ post_W2,
    unsigned short* __restrict__ wsdt, unsigned short* __restrict__ wt2,
    unsigned short* __restrict__ wt3) {
  int b = blockIdx.x;
  if (b < degBlocks) {
    int i = b * 256 + threadIdx.x;
    if (i < E) rank[i] = atomicAdd(&deg[dst[i]], 1);
    return;
  }
  int idx = (b - degBlocks) * 256 + threadIdx.x;
  if (idx < 128 * 64) {
    int c = idx >> 6, k = idx & 63;
    float v = (c < 64) ? pre_W[k * 64 + c] : pre_W[(64 + k) * 64 + (c - 64)];
    wsdt[idx] = f2h(v);
  }
  int j = idx - 128 * 64;
  if (j >= 0 && j < 192 * 320) {
    int c = j / 320, k = j - c * 320;
    float v;
    if (c < 64) v = post_W1[k * 64 + c];
    else if (c < 128) v = (k < 64) ? 0.f : post_W1[(256 + k) * 64 + (c - 64)];
    else v = (k < 64) ? 0.f : post_W1[(512 + k) * 64 + (c - 128)];
    wt2[j] = f2h(v);
  }
  int m = idx - 128 * 64 - 192 * 320;
  if (m >= 0 && m < 64 * 64) {
    int c = m >> 6, k = m & 63;
    wt3[m] = f2h(post_W2[k * 64 + c]);
  }
}

__global__ __launch_bounds__(1024) void k_scan_a(const int* __restrict__ deg,
                                                 int* __restrict__ offs,
                                                 int* __restrict__ bsum,
                                                 float* __restrict__ aux2, int N) {
  __shared__ int s[1024];
  int t = threadIdx.x;
  int i = blockIdx.x * 1024 + t;
  int v = (i < N) ? deg[i] : 0;
  s[t] = v;
  __syncthreads();
  for (int off = 1; off < 1024; off <<= 1) {
    int x = (t >= off) ? s[t - off] : 0;
    __syncthreads();
    s[t] += x;
    __syncthreads();
  }
  if (i < N) {
    offs[i] = s[t] - v;
    float logD = logf((float)v + 1.f);
    aux2[i * 2] = logD;                                         // amp scaler
    aux2[i * 2 + 1] = (v > 0) ? 1.f / fmaxf(logD, EPSF) : 0.f;  // att scaler
  }
  if (t == 1023) bsum[blockIdx.x] = s[1023];
}

__global__ __launch_bounds__(1024) void k_scan_b(int* __restrict__ bsum, int nb) {
  __shared__ int s[1024];
  int t = threadIdx.x;
  int v = (t < nb) ? bsum[t] : 0;
  s[t] = v;
  __syncthreads();
  for (int off = 1; off < 1024; off <<= 1) {
    int x = (t >= off) ? s[t - off] : 0;
    __syncthreads();
    s[t] += x;
    __syncthreads();
  }
  if (t < nb) bsum[t] = s[t] - v;
}

__global__ __launch_bounds__(1024) void k_scan_c(int* __restrict__ offs,
                                                 const int* __restrict__ bsum,
                                                 int N) {
  int i = blockIdx.x * 1024 + threadIdx.x;
  if (i < N) offs[i] += bsum[blockIdx.x];
}

// ---------------- node projections: P_s = nf@Ws, P_d = nf@Wd + b (MFMA f16) --

__global__ __launch_bounds__(256) void kB_proj(
    const float* __restrict__ nf, const unsigned short* __restrict__ wsdt,
    const float* __restrict__ pre_b, unsigned short* __restrict__ ps,
    unsigned short* __restrict__ pd, int N) {
  __shared__ unsigned short at[64][72];
  int tid = threadIdx.x;
  int n0 = blockIdx.x * 64;
  for (int idx = tid; idx < 64 * 16; idx += 256) {
    int row = idx >> 4, s4 = idx & 15;
    int n = n0 + row;
    us4 o = {0, 0, 0, 0};
    if (n < N) {
      f32x4 v = *(const f32x4*)(nf + (long)n * 64 + s4 * 4);
      o.x = f2h(v.x); o.y = f2h(v.y); o.z = f2h(v.z); o.w = f2h(v.w);
    }
    *(us4*)&at[row][s4 * 4] = o;
    if (s4 < 2) { us4 z = {0, 0, 0, 0}; *(us4*)&at[row][64 + s4 * 4] = z; }
  }
  __syncthreads();
  int lane = tid & 63, w = tid >> 6;
  int r0 = w * 16;
  const unsigned short* ap = &at[r0 + (lane & 15)][(lane >> 4) * 8];
  const unsigned short* bp = wsdt + (lane & 15) * 64 + (lane >> 4) * 8;
  f32x4 acc[8];
#pragma unroll
  for (int c = 0; c < 8; c++) acc[c] = (f32x4){0.f, 0.f, 0.f, 0.f};
#pragma unroll
  for (int c = 0; c < 8; c++) {
#pragma unroll
    for (int kk = 0; kk < 2; kk++) {
      h16x8 a = *(const h16x8*)(ap + kk * 32);
      h16x8 b = *(const h16x8*)(bp + c * 1024 + kk * 32);
      acc[c] = __builtin_amdgcn_mfma_f32_16x16x32_f16(a, b, acc[c], 0, 0, 0);
    }
  }
  int rb = r0 + ((lane >> 4) << 2);
#pragma unroll
  for (int c = 0; c < 8; c++) {
    int col = c * 16 + (lane & 15);
    int cc = col & 63;
    float bv = (col >= 64) ? pre_b[cc] : 0.f;
#pragma unroll
    for (int r = 0; r < 4; r++) {
      int n = n0 + rb + r;
      if (n < N) {
        unsigned short val = f2h(acc[c][r] + bv);
        if (col >= 64) pd[(long)n * 64 + cc] = val;
        else ps[(long)n * 64 + cc] = val;
      }
    }
  }
}

// ---------------- phase 1a: partial = q + ps[src], scatter to CSR ------------
// R19 form: ps gathers pre-issued before the MFMA section (latency hidden by
// TLP + MFMA); NO cross-group software pipeline (costs VGPR/occupancy, R20).

__global__ __launch_bounds__(256) void kQe(
    const float* __restrict__ efeat, const float* __restrict__ pre_W,
    const unsigned short* __restrict__ ps,
    const int* __restrict__ src, const int* __restrict__ dst,
    const int* __restrict__ rank, const int* __restrict__ offs,
    unsigned short* __restrict__ rbuf, int E) {
  __shared__ unsigned short vt[4][16][72];
  int lane = threadIdx.x & 63, w = threadIdx.x >> 6;
  int colb = lane & 15, kg = lane >> 4;

  h16x8 bfrag[4];
#pragma unroll
  for (int ct = 0; ct < 4; ct++) {
    _Float16 tmp[8];
#pragma unroll
    for (int j = 0; j < 8; j++) {
      int k = kg * 8 + j;
      tmp[j] = (k < 16) ? (_Float16)pre_W[(128 + k) * 64 + ct * 16 + colb]
                        : (_Float16)0.f;
    }
    bfrag[ct] = *(h16x8*)tmp;
  }

  const int GROUPS = 4;
  long pbase = ((long)blockIdx.x * 4 + w) * (16 * GROUPS);
#pragma unroll 1
  for (int g = 0; g < GROUPS; g++) {
    long p0 = pbase + (long)g * 16;
    if (p0 >= E) return;

    long pl = p0 + colb;
    int sv = 0, posv = 0;
    if (pl < E) {
      sv = __builtin_nontemporal_load(src + pl);
      int dv = __builtin_nontemporal_load(dst + pl);
      posv = offs[dv] + __builtin_nontemporal_load(rank + pl);
    }

    // pre-issue all 16 ps gathers (lane = channel); latency hides under MFMA
    unsigned short psv[16];
#pragma unroll
    for (int i = 0; i < 16; i++) {
      int s_i = ibcast(sv, i);
      psv[i] = ps[(long)s_i * 64 + lane];
    }

    h16x8 afrag;
    {
      _Float16 tmp[8] = {0, 0, 0, 0, 0, 0, 0, 0};
      if (kg < 2 && pl < E) {
        f32x4 v0 = __builtin_nontemporal_load(
            (const f32x4*)(efeat + pl * 16 + kg * 8));
        f32x4 v1 = __builtin_nontemporal_load(
            (const f32x4*)(efeat + pl * 16 + kg * 8 + 4));
        tmp[0] = (_Float16)v0.x; tmp[1] = (_Float16)v0.y;
        tmp[2] = (_Float16)v0.z; tmp[3] = (_Float16)v0.w;
        tmp[4] = (_Float16)v1.x; tmp[5] = (_Float16)v1.y;
        tmp[6] = (_Float16)v1.z; tmp[7] = (_Float16)v1.w;
      }
      afrag = *(h16x8*)tmp;
    }

    f32x4 acc[4];
#pragma unroll
    for (int ct = 0; ct < 4; ct++) acc[ct] = (f32x4){0.f, 0.f, 0.f, 0.f};
#pragma unroll
    for (int ct = 0; ct < 4; ct++)
      acc[ct] = __builtin_amdgcn_mfma_f32_16x16x32_f16(afrag, bfrag[ct],
                                                       acc[ct], 0, 0, 0);

    // stage q (fp16) into vt: row = kg*4+r, col = ct*16+colb
#pragma unroll
    for (int ct = 0; ct < 4; ct++)
#pragma unroll
      for (int r = 0; r < 4; r++)
        vt[w][kg * 4 + r][ct * 16 + colb] = f2h(acc[ct][r]);

    // partial = q + ps[src] back into vt, lane = channel
#pragma unroll
    for (int i = 0; i < 16; i++) {
      long p = p0 + i;
      if (p >= E) break;
      float v = h2f(vt[w][i][lane]) + h2f(psv[i]);
      vt[w][i][lane] = f2h(v);
    }

    // vectorized scatter: 2 wave-stores, each covers 8 rows x 128B.
#pragma unroll
    for (int pass = 0; pass < 2; pass++) {
      int row = pass * 8 + (lane >> 3);
      long p = p0 + row;
      long pos = (long)lanegather(posv, row);
      if (p < E) {
        us8 val = *(const us8*)&vt[w][row][(lane & 7) * 8];
        *(us8*)(rbuf + pos * 64 + (lane & 7) * 8) = val;
      }
    }
  }
}

// ---------------- phase 1b: sequential segmented stats (+pd, +relu) ----------

__global__ __launch_bounds__(256) void kAgg(
    const unsigned short* __restrict__ rbuf, const unsigned short* __restrict__ pd,
    const int* __restrict__ offs, const int* __restrict__ deg,
    unsigned short* __restrict__ aggb, int N) {
  int lane = threadIdx.x & 63;
  int n = blockIdx.x * 4 + (threadIdx.x >> 6);
  if (n >= N) return;
  int dc = deg[n];
  long ab = (long)n * 256 + lane;
  if (dc == 0) {
    aggb[ab] = 0; aggb[ab + 64] = 0; aggb[ab + 128] = 0; aggb[ab + 192] = 0;
    return;
  }
  float pdv = h2f(pd[(long)n * 64 + lane]);
  long p = offs[n], pe = p + dc;
  float sa = 0.f, qa = 0.f, mx = 0.f, mn = 3.4e38f;
  for (; p + 4 <= pe; p += 4) {
    float v0 = fmaxf(h2f(rbuf[p * 64 + lane]) + pdv, 0.f);
    float v1 = fmaxf(h2f(rbuf[(p + 1) * 64 + lane]) + pdv, 0.f);
    float v2 = fmaxf(h2f(rbuf[(p + 2) * 64 + lane]) + pdv, 0.f);
    float v3 = fmaxf(h2f(rbuf[(p + 3) * 64 + lane]) + pdv, 0.f);
    sa += (v0 + v1) + (v2 + v3);
    qa = fmaf(v0, v0, qa); qa = fmaf(v1, v1, qa);
    qa = fmaf(v2, v2, qa); qa = fmaf(v3, v3, qa);
    mx = fmaxf(mx, fmaxf(fmaxf(v0, v1), fmaxf(v2, v3)));
    mn = fminf(mn, fminf(fminf(v0, v1), fminf(v2, v3)));
  }
  for (; p < pe; p++) {
    float v0 = fmaxf(h2f(rbuf[p * 64 + lane]) + pdv, 0.f);
    sa += v0;
    qa = fmaf(v0, v0, qa);
    mx = fmaxf(mx, v0);
    mn = fminf(mn, v0);
  }
  float invd = 1.f / (float)dc;
  float mean = sa * invd;
  float var = fmaxf(qa * invd - mean * mean, 0.f);
  float stdv = sqrtf(var + EPSF);
  aggb[ab] = f2h(mean);
  aggb[ab + 64] = f2h(mx);
  aggb[ab + 128] = f2h(mn);
  aggb[ab + 192] = f2h(stdv);
}

// ---------------- phase 2: post1 GEMM, K=320, B register-resident ------------

__global__ __launch_bounds__(256) void kC_post1(
    const float* __restrict__ nf, const unsigned short* __restrict__ aggb,
    const float* __restrict__ aux2, const unsigned short* __restrict__ wt2,
    const float* __restrict__ b1, unsigned short* __restrict__ x1,
    float* __restrict__ bn_sum, float* __restrict__ bn_ssq, int N) {
  __shared__ unsigned short At[64][328];  // 41 KB; reused as float[64][68] later
  int tid = threadIdx.x;
  int n0 = blockIdx.x * 64;
  int lane = tid & 63, w = tid >> 6;
  int colb = lane & 15, kg = lane >> 4;

  const unsigned short* bp0 = wt2 + (long)(w * 16 + colb) * 320 + kg * 8;
  const unsigned short* bp1 = wt2 + (long)(64 + w * 16 + colb) * 320 + kg * 8;
  const unsigned short* bp2 = wt2 + (long)(128 + w * 16 + colb) * 320 + kg * 8;
  h16x8 bf0[10], bf1[8], bf2[8];
#pragma unroll
  for (int kk = 0; kk < 10; kk++) bf0[kk] = *(const h16x8*)(bp0 + kk * 32);
#pragma unroll
  for (int j = 0; j < 8; j++) bf1[j] = *(const h16x8*)(bp1 + (j + 2) * 32);
#pragma unroll
  for (int j = 0; j < 8; j++) bf2[j] = *(const h16x8*)(bp2 + (j + 2) * 32);

  for (int idx = tid; idx < 64 * 40; idx += 256) {
    int row = idx / 40, s = idx - row * 40;
    int n = n0 + row;
    us8 o = {0, 0, 0, 0, 0, 0, 0, 0};
    if (n < N) {
      if (s < 8) {
        f32x4 v0 = *(const f32x4*)(nf + (long)n * 64 + s * 8);
        f32x4 v1 = *(const f32x4*)(nf + (long)n * 64 + s * 8 + 4);
        o[0] = f2h(v0.x); o[1] = f2h(v0.y); o[2] = f2h(v0.z); o[3] = f2h(v0.w);
        o[4] = f2h(v1.x); o[5] = f2h(v1.y); o[6] = f2h(v1.z); o[7] = f2h(v1.w);
      } else {
        o = *((const us8*)(aggb + (long)n * 256) + (s - 8));
      }
    }
    *(us8*)&At[row][s * 8] = o;
  }
  __syncthreads();

  f32x4 acc0[4], acc1[4], acc2[4];
#pragma unroll
  for (int s = 0; s < 4; s++) {
    acc0[s] = (f32x4){0.f, 0.f, 0.f, 0.f};
    acc1[s] = (f32x4){0.f, 0.f, 0.f, 0.f};
    acc2[s] = (f32x4){0.f, 0.f, 0.f, 0.f};
  }
#pragma unroll
  for (int s = 0; s < 4; s++) {
    const unsigned short* ap = &At[s * 16 + colb][kg * 8];
#pragma unroll
    for (int kk = 0; kk < 10; kk++) {
      h16x8 a = *(const h16x8*)(ap + kk * 32);
      acc0[s] = __builtin_amdgcn_mfma_f32_16x16x32_f16(a, bf0[kk], acc0[s], 0, 0, 0);
      if (kk >= 2) {
        acc1[s] = __builtin_amdgcn_mfma_f32_16x16x32_f16(a, bf1[kk - 2], acc1[s], 0, 0, 0);
        acc2[s] = __builtin_amdgcn_mfma_f32_16x16x32_f16(a, bf2[kk - 2], acc2[s], 0, 0, 0);
      }
    }
  }
  __syncthreads();

  float* sx = (float*)&At[0][0];
  int col = w * 16 + colb;
  float bv = b1[col];
#pragma unroll
  for (int s = 0; s < 4; s++) {
    int rb = s * 16 + kg * 4;
#pragma unroll
    for (int r = 0; r < 4; r++) {
      int n = n0 + rb + r;
      float x = 0.f;
      if (n < N) {
        float lg = aux2[(long)n * 2];
        float atf = aux2[(long)n * 2 + 1];
        x = fmaxf(acc0[s][r] + lg * acc1[s][r] + atf * acc2[s][r] + bv, 0.f);
      }
      sx[(rb + r) * 68 + col] = x;
    }
  }
  __syncthreads();

  for (int idx = tid; idx < 64 * 16; idx += 256) {
    int row = idx >> 4, s4 = idx & 15;
    int n = n0 + row;
    if (n < N) {
      const float* p = sx + row * 68 + s4 * 4;
      us4 o;
      o.x = f2h(p[0]); o.y = f2h(p[1]); o.z = f2h(p[2]); o.w = f2h(p[3]);
      *(us4*)(x1 + (long)n * 64 + s4 * 4) = o;
    }
  }
  if (tid < 64) {
    float s = 0.f, s2 = 0.f;
    for (int r = 0; r < 64; r++) {
      float v = sx[r * 68 + tid];
      s += v;
      s2 = fmaf(v, v, s2);
    }
    atomicAdd(&bn_sum[tid], s);
    atomicAdd(&bn_ssq[tid], s2);
  }
}

// ---------------- BN stats finalize -----------------------------------------

__global__ __launch_bounds__(64) void k_bnstat(
    const float* __restrict__ bn_sum, const float* __restrict__ bn_ssq,
    const float* __restrict__ gamma, const float* __restrict__ beta,
    float* __restrict__ scale, float* __restrict__ shift, float invN) {
  int j = threadIdx.x;
  float mu = bn_sum[j] * invN;
  float v = fmaxf(bn_ssq[j] * invN - mu * mu, 0.f);
  float sc = gamma[j] / sqrtf(v + EPSF);
  scale[j] = sc;
  shift[j] = beta[j] - mu * sc;
}

// ---------------- out = relu(BN(x1)@W2 + b2) + h_in (MFMA tile) --------------

__global__ __launch_bounds__(256) void k_post2(
    const unsigned short* __restrict__ x1, const unsigned short* __restrict__ wt3,
    const float* __restrict__ post_b2, const float* __restrict__ scale,
    const float* __restrict__ shift, const float* __restrict__ nf,
    float* __restrict__ out, int N) {
  __shared__ unsigned short at[64][72];
  int tid = threadIdx.x;
  int n0 = blockIdx.x * 64;
  for (int idx = tid; idx < 64 * 16; idx += 256) {
    int row = idx >> 4, s4 = idx & 15;
    int n = n0 + row;
    us4 o = {0, 0, 0, 0};
    if (n < N) {
      us4 xv = *(const us4*)(x1 + (long)n * 64 + s4 * 4);
      f32x4 sc = *(const f32x4*)(scale + s4 * 4);
      f32x4 sh = *(const f32x4*)(shift + s4 * 4);
      o.x = f2h(fmaf(h2f(xv.x), sc.x, sh.x));
      o.y = f2h(fmaf(h2f(xv.y), sc.y, sh.y));
      o.z = f2h(fmaf(h2f(xv.z), sc.z, sh.z));
      o.w = f2h(fmaf(h2f(xv.w), sc.w, sh.w));
    }
    *(us4*)&at[row][s4 * 4] = o;
  }
  __syncthreads();
  int lane = tid & 63, w = tid >> 6;
  int colb = lane & 15, kg = lane >> 4;
  int r0 = w * 16;
  const unsigned short* ap = &at[r0 + colb][kg * 8];
  const unsigned short* bp = wt3 + colb * 64 + kg * 8;
  f32x4 acc[4];
#pragma unroll
  for (int ct = 0; ct < 4; ct++) acc[ct] = (f32x4){0.f, 0.f, 0.f, 0.f};
#pragma unroll
  for (int kk = 0; kk < 2; kk++) {
    h16x8 a = *(const h16x8*)(ap + kk * 32);
#pragma unroll
    for (int ct = 0; ct < 4; ct++) {
      h16x8 b = *(const h16x8*)(bp + ct * (16 * 64) + kk * 32);
      acc[ct] = __builtin_amdgcn_mfma_f32_16x16x32_f16(a, b, acc[ct], 0, 0, 0);
    }
  }
  int rb = r0 + kg * 4;
#pragma unroll
  for (int ct = 0; ct < 4; ct++) {
    int col = ct * 16 + colb;
    float bv = post_b2[col];
#pragma unroll
    for (int r = 0; r < 4; r++) {
      int n = n0 + rb + r;
      if (n < N)
        out[(long)n * 64 + col] =
            fmaxf(acc[ct][r] + bv, 0.f) + nf[(long)n * 64 + col];
    }
  }
}

// ----------------------------------------------------------------------------

extern "C" void kernel_launch(void* const* d_in, const int* in_sizes, int n_in,
                              void* d_out, int out_size, void* d_ws, size_t ws_size,
                              hipStream_t stream) {
  const float* node_feat = (const float*)d_in[0];
  const float* edge_feat = (const float*)d_in[1];
  const float* pre_W = (const float*)d_in[2];
  const float* pre_b = (const float*)d_in[3];
  const float* post_W1 = (const float*)d_in[4];
  const float* post_b1 = (const float*)d_in[5];
  const float* bn_gamma = (const float*)d_in[6];
  const float* bn_beta = (const float*)d_in[7];
  const float* post_W2 = (const float*)d_in[8];
  const float* post_b2 = (const float*)d_in[9];
  const int* src = (const int*)d_in[10];
  const int* dst = (const int*)d_in[11];
  float* out = (float*)d_out;

  int N = in_sizes[0] / 64;
  int E = in_sizes[10];

  char* ws = (char*)d_ws;
  size_t off = 0;
  auto alloc = [&](size_t bytes) -> void* {
    void* p = ws + off;
    off += (bytes + 255) & ~(size_t)255;
    return p;
  };
  int* deg = (int*)alloc((size_t)N * 4);
  float* bn_sum = (float*)alloc(64 * 4);
  float* bn_ssq = (float*)alloc(64 * 4);
  size_t zero_span = off;
  int* offs = (int*)alloc((size_t)N * 4);
  int* rank = (int*)alloc((size_t)E * 4);
  int* bsum = (int*)alloc(1024 * 4);
  unsigned short* aggb = (unsigned short*)alloc((size_t)N * 256 * 2);
  float* aux2 = (float*)alloc((size_t)N * 2 * 4);
  unsigned short* psb = (unsigned short*)alloc((size_t)N * 64 * 2);
  unsigned short* pdb = (unsigned short*)alloc((size_t)N * 64 * 2);
  unsigned short* x1 = (unsigned short*)alloc((size_t)N * 64 * 2);
  unsigned short* wsdt = (unsigned short*)alloc(128 * 64 * 2);
  unsigned short* wt2 = (unsigned short*)alloc(192 * 320 * 2);
  unsigned short* wt3 = (unsigned short*)alloc(64 * 64 * 2);
  float* bn_scale = (float*)alloc(64 * 4);
  float* bn_shift = (float*)alloc(64 * 4);
  unsigned short* rbuf = (unsigned short*)alloc((size_t)E * 64 * 2);
  if (off > ws_size) return;  // fail loudly (output stays poisoned)

  int nscan = (N + 1023) / 1024;
  int degBlocks = (E + 255) / 256;
  int prepBlocks = (128 * 64 + 192 * 320 + 64 * 64 + 255) / 256;

  hipMemsetAsync(deg, 0, zero_span, stream);
  k_front<<<degBlocks + prepBlocks, 256, 0, stream>>>(
      dst, deg, rank, E, degBlocks, pre_W, post_W1, post_W2, wsdt, wt2, wt3);
  k_scan_a<<<nscan, 1024, 0, stream>>>(deg, offs, bsum, aux2, N);
  k_scan_b<<<1, 1024, 0, stream>>>(bsum, nscan);
  k_scan_c<<<nscan, 1024, 0, stream>>>(offs, bsum, N);
  kB_proj<<<(N + 63) / 64, 256, 0, stream>>>(node_feat, wsdt, pre_b, psb, pdb, N);

  kQe<<<(E + 255) / 256, 256, 0, stream>>>(edge_feat, pre_W, psb, src, dst,
                                           rank, offs, rbuf, E);
  kAgg<<<(N + 3) / 4, 256, 0, stream>>>(rbuf, pdb, offs, deg, aggb, N);

  kC_post1<<<(N + 63) / 64, 256, 0, stream>>>(node_feat, aggb, aux2, wt2,
                                              post_b1, x1, bn_sum, bn_ssq, N);

  k_bnstat<<<1, 64, 0, stream>>>(bn_sum, bn_ssq, bn_gamma, bn_beta, bn_scale,
                                 bn_shift, 1.0f / (float)N);

  k_post2<<<(N + 63) / 64, 256, 0, stream>>>(x1, wt3, post_b2, bn_scale,
                                             bn_shift, node_feat, out, N);
}

// Round 22
// 424.727 us; speedup vs baseline: 1.0597x; 1.0171x over previous
//
#include <hip/hip_runtime.h>
#include <math.h>

#define EPSF 1e-5f

typedef __attribute__((ext_vector_type(8))) _Float16 h16x8;
typedef __attribute__((ext_vector_type(4))) float f32x4;
typedef __attribute__((ext_vector_type(4))) unsigned short us4;
typedef __attribute__((ext_vector_type(8))) unsigned short us8;

static __device__ __forceinline__ unsigned short f2h(float f) {
  _Float16 h = (_Float16)f;
  return __builtin_bit_cast(unsigned short, h);
}
static __device__ __forceinline__ float h2f(unsigned short u) {
  _Float16 h = __builtin_bit_cast(_Float16, u);
  return (float)h;
}
static __device__ __forceinline__ int ibcast(int v, int l) {  // uniform l only
  return __builtin_amdgcn_readlane(v, l);
}
static __device__ __forceinline__ int lanegather(int v, int srcLane) {
  return __builtin_amdgcn_ds_bpermute(srcLane << 2, v);
}

// ---------------- merged: histogram(+rank) + weight prep ---------------------

__global__ __launch_bounds__(256) void k_front(
    const int* __restrict__ dst, int* __restrict__ deg, int* __restrict__ rank,
    int E, int degBlocks, const float* __restrict__ pre_W,
    const float* __restrict__ post_W1, const float* __restrict__ post_W2,
    unsigned short* __restrict__ wsdt, unsigned short* __restrict__ wt2,
    unsigned short* __restrict__ wt3) {
  int b = blockIdx.x;
  if (b < degBlocks) {
    int i = b * 256 + threadIdx.x;
    if (i < E) rank[i] = atomicAdd(&deg[dst[i]], 1);
    return;
  }
  int idx = (b - degBlocks) * 256 + threadIdx.x;
  if (idx < 128 * 64) {
    int c = idx >> 6, k = idx & 63;
    float v = (c < 64) ? pre_W[k * 64 + c] : pre_W[(64 + k) * 64 + (c - 64)];
    wsdt[idx] = f2h(v);
  }
  int j = idx - 128 * 64;
  if (j >= 0 && j < 192 * 320) {
    int c = j / 320, k = j - c * 320;
    float v;
    if (c < 64) v = post_W1[k * 64 + c];
    else if (c < 128) v = (k < 64) ? 0.f : post_W1[(256 + k) * 64 + (c - 64)];
    else v = (k < 64) ? 0.f : post_W1[(512 + k) * 64 + (c - 128)];
    wt2[j] = f2h(v);
  }
  int m = idx - 128 * 64 - 192 * 320;
  if (m >= 0 && m < 64 * 64) {
    int c = m >> 6, k = m & 63;
    wt3[m] = f2h(post_W2[k * 64 + c]);
  }
}

// offs[i] = block-local exclusive scan; consumers add bsum[i>>10] (no scan_c).
__global__ __launch_bounds__(1024) void k_scan_a(const int* __restrict__ deg,
                                                 int* __restrict__ offs,
                                                 int* __restrict__ bsum,
                                                 float* __restrict__ aux2, int N) {
  __shared__ int s[1024];
  int t = threadIdx.x;
  int i = blockIdx.x * 1024 + t;
  int v = (i < N) ? deg[i] : 0;
  s[t] = v;
  __syncthreads();
  for (int off = 1; off < 1024; off <<= 1) {
    int x = (t >= off) ? s[t - off] : 0;
    __syncthreads();
    s[t] += x;
    __syncthreads();
  }
  if (i < N) {
    offs[i] = s[t] - v;
    float logD = logf((float)v + 1.f);
    aux2[i * 2] = logD;                                         // amp scaler
    aux2[i * 2 + 1] = (v > 0) ? 1.f / fmaxf(logD, EPSF) : 0.f;  // att scaler
  }
  if (t == 1023) bsum[blockIdx.x] = s[1023];
}

__global__ __launch_bounds__(1024) void k_scan_b(int* __restrict__ bsum, int nb) {
  __shared__ int s[1024];
  int t = threadIdx.x;
  int v = (t < nb) ? bsum[t] : 0;
  s[t] = v;
  __syncthreads();
  for (int off = 1; off < 1024; off <<= 1) {
    int x = (t >= off) ? s[t - off] : 0;
    __syncthreads();
    s[t] += x;
    __syncthreads();
  }
  if (t < nb) bsum[t] = s[t] - v;
}

// ---------------- node projections: P_s = nf@Ws, P_d = nf@Wd + b (MFMA f16) --

__global__ __launch_bounds__(256) void kB_proj(
    const float* __restrict__ nf, const unsigned short* __restrict__ wsdt,
    const float* __restrict__ pre_b, unsigned short* __restrict__ ps,
    unsigned short* __restrict__ pd, int N) {
  __shared__ unsigned short at[64][72];
  int tid = threadIdx.x;
  int n0 = blockIdx.x * 64;
  for (int idx = tid; idx < 64 * 16; idx += 256) {
    int row = idx >> 4, s4 = idx & 15;
    int n = n0 + row;
    us4 o = {0, 0, 0, 0};
    if (n < N) {
      f32x4 v = *(const f32x4*)(nf + (long)n * 64 + s4 * 4);
      o.x = f2h(v.x); o.y = f2h(v.y); o.z = f2h(v.z); o.w = f2h(v.w);
    }
    *(us4*)&at[row][s4 * 4] = o;
    if (s4 < 2) { us4 z = {0, 0, 0, 0}; *(us4*)&at[row][64 + s4 * 4] = z; }
  }
  __syncthreads();
  int lane = tid & 63, w = tid >> 6;
  int r0 = w * 16;
  const unsigned short* ap = &at[r0 + (lane & 15)][(lane >> 4) * 8];
  const unsigned short* bp = wsdt + (lane & 15) * 64 + (lane >> 4) * 8;
  f32x4 acc[8];
#pragma unroll
  for (int c = 0; c < 8; c++) acc[c] = (f32x4){0.f, 0.f, 0.f, 0.f};
#pragma unroll
  for (int c = 0; c < 8; c++) {
#pragma unroll
    for (int kk = 0; kk < 2; kk++) {
      h16x8 a = *(const h16x8*)(ap + kk * 32);
      h16x8 b = *(const h16x8*)(bp + c * 1024 + kk * 32);
      acc[c] = __builtin_amdgcn_mfma_f32_16x16x32_f16(a, b, acc[c], 0, 0, 0);
    }
  }
  int rb = r0 + ((lane >> 4) << 2);
#pragma unroll
  for (int c = 0; c < 8; c++) {
    int col = c * 16 + (lane & 15);
    int cc = col & 63;
    float bv = (col >= 64) ? pre_b[cc] : 0.f;
#pragma unroll
    for (int r = 0; r < 4; r++) {
      int n = n0 + rb + r;
      if (n < N) {
        unsigned short val = f2h(acc[c][r] + bv);
        if (col >= 64) pd[(long)n * 64 + cc] = val;
        else ps[(long)n * 64 + cc] = val;
      }
    }
  }
}

// ---------------- phase 1a: partial = q + ps[src], scatter to CSR ------------
// R19 structure; GROUPS=8 (bfrag amortization); offs fix-up via bsum table.

__global__ __launch_bounds__(256) void kQe(
    const float* __restrict__ efeat, const float* __restrict__ pre_W,
    const unsigned short* __restrict__ ps,
    const int* __restrict__ src, const int* __restrict__ dst,
    const int* __restrict__ rank, const int* __restrict__ offs,
    const int* __restrict__ bsum, unsigned short* __restrict__ rbuf, int E) {
  __shared__ unsigned short vt[4][16][72];
  int lane = threadIdx.x & 63, w = threadIdx.x >> 6;
  int colb = lane & 15, kg = lane >> 4;

  h16x8 bfrag[4];
#pragma unroll
  for (int ct = 0; ct < 4; ct++) {
    _Float16 tmp[8];
#pragma unroll
    for (int j = 0; j < 8; j++) {
      int k = kg * 8 + j;
      tmp[j] = (k < 16) ? (_Float16)pre_W[(128 + k) * 64 + ct * 16 + colb]
                        : (_Float16)0.f;
    }
    bfrag[ct] = *(h16x8*)tmp;
  }

  const int GROUPS = 8;
  long pbase = ((long)blockIdx.x * 4 + w) * (16 * GROUPS);
#pragma unroll 1
  for (int g = 0; g < GROUPS; g++) {
    long p0 = pbase + (long)g * 16;
    if (p0 >= E) return;

    long pl = p0 + colb;
    int sv = 0, posv = 0;
    if (pl < E) {
      sv = __builtin_nontemporal_load(src + pl);
      int dv = __builtin_nontemporal_load(dst + pl);
      posv = offs[dv] + bsum[dv >> 10] + __builtin_nontemporal_load(rank + pl);
    }

    // pre-issue all 16 ps gathers (lane = channel); latency hides under MFMA
    unsigned short psv[16];
#pragma unroll
    for (int i = 0; i < 16; i++) {
      int s_i = ibcast(sv, i);
      psv[i] = ps[(long)s_i * 64 + lane];
    }

    h16x8 afrag;
    {
      _Float16 tmp[8] = {0, 0, 0, 0, 0, 0, 0, 0};
      if (kg < 2 && pl < E) {
        f32x4 v0 = __builtin_nontemporal_load(
            (const f32x4*)(efeat + pl * 16 + kg * 8));
        f32x4 v1 = __builtin_nontemporal_load(
            (const f32x4*)(efeat + pl * 16 + kg * 8 + 4));
        tmp[0] = (_Float16)v0.x; tmp[1] = (_Float16)v0.y;
        tmp[2] = (_Float16)v0.z; tmp[3] = (_Float16)v0.w;
        tmp[4] = (_Float16)v1.x; tmp[5] = (_Float16)v1.y;
        tmp[6] = (_Float16)v1.z; tmp[7] = (_Float16)v1.w;
      }
      afrag = *(h16x8*)tmp;
    }

    f32x4 acc[4];
#pragma unroll
    for (int ct = 0; ct < 4; ct++) acc[ct] = (f32x4){0.f, 0.f, 0.f, 0.f};
#pragma unroll
    for (int ct = 0; ct < 4; ct++)
      acc[ct] = __builtin_amdgcn_mfma_f32_16x16x32_f16(afrag, bfrag[ct],
                                                       acc[ct], 0, 0, 0);

    // stage q (fp16) into vt: row = kg*4+r, col = ct*16+colb
#pragma unroll
    for (int ct = 0; ct < 4; ct++)
#pragma unroll
      for (int r = 0; r < 4; r++)
        vt[w][kg * 4 + r][ct * 16 + colb] = f2h(acc[ct][r]);

    // partial = q + ps[src] back into vt, lane = channel
#pragma unroll
    for (int i = 0; i < 16; i++) {
      long p = p0 + i;
      if (p >= E) break;
      float v = h2f(vt[w][i][lane]) + h2f(psv[i]);
      vt[w][i][lane] = f2h(v);
    }

    // vectorized scatter: 2 wave-stores, each covers 8 rows x 128B.
#pragma unroll
    for (int pass = 0; pass < 2; pass++) {
      int row = pass * 8 + (lane >> 3);
      long p = p0 + row;
      long pos = (long)lanegather(posv, row);
      if (p < E) {
        us8 val = *(const us8*)&vt[w][row][(lane & 7) * 8];
        *(us8*)(rbuf + pos * 64 + (lane & 7) * 8) = val;
      }
    }
  }
}

// ---------------- phase 1b: sequential segmented stats (+pd, +relu) ----------

__global__ __launch_bounds__(256) void kAgg(
    const unsigned short* __restrict__ rbuf, const unsigned short* __restrict__ pd,
    const int* __restrict__ offs, const int* __restrict__ bsum,
    const int* __restrict__ deg, unsigned short* __restrict__ aggb, int N) {
  int lane = threadIdx.x & 63;
  int n = blockIdx.x * 4 + (threadIdx.x >> 6);
  if (n >= N) return;
  int dc = deg[n];
  long ab = (long)n * 256 + lane;
  if (dc == 0) {
    aggb[ab] = 0; aggb[ab + 64] = 0; aggb[ab + 128] = 0; aggb[ab + 192] = 0;
    return;
  }
  float pdv = h2f(pd[(long)n * 64 + lane]);
  long p = (long)offs[n] + bsum[n >> 10], pe = p + dc;
  float sa = 0.f, qa = 0.f, mx = 0.f, mn = 3.4e38f;
  for (; p + 4 <= pe; p += 4) {
    float v0 = fmaxf(h2f(rbuf[p * 64 + lane]) + pdv, 0.f);
    float v1 = fmaxf(h2f(rbuf[(p + 1) * 64 + lane]) + pdv, 0.f);
    float v2 = fmaxf(h2f(rbuf[(p + 2) * 64 + lane]) + pdv, 0.f);
    float v3 = fmaxf(h2f(rbuf[(p + 3) * 64 + lane]) + pdv, 0.f);
    sa += (v0 + v1) + (v2 + v3);
    qa = fmaf(v0, v0, qa); qa = fmaf(v1, v1, qa);
    qa = fmaf(v2, v2, qa); qa = fmaf(v3, v3, qa);
    mx = fmaxf(mx, fmaxf(fmaxf(v0, v1), fmaxf(v2, v3)));
    mn = fminf(mn, fminf(fminf(v0, v1), fminf(v2, v3)));
  }
  for (; p < pe; p++) {
    float v0 = fmaxf(h2f(rbuf[p * 64 + lane]) + pdv, 0.f);
    sa += v0;
    qa = fmaf(v0, v0, qa);
    mx = fmaxf(mx, v0);
    mn = fminf(mn, v0);
  }
  float invd = 1.f / (float)dc;
  float mean = sa * invd;
  float var = fmaxf(qa * invd - mean * mean, 0.f);
  float stdv = sqrtf(var + EPSF);
  aggb[ab] = f2h(mean);
  aggb[ab + 64] = f2h(mx);
  aggb[ab + 128] = f2h(mn);
  aggb[ab + 192] = f2h(stdv);
}

// ---------------- phase 2: post1 GEMM, K=320, B register-resident ------------

__global__ __launch_bounds__(256) void kC_post1(
    const float* __restrict__ nf, const unsigned short* __restrict__ aggb,
    const float* __restrict__ aux2, const unsigned short* __restrict__ wt2,
    const float* __restrict__ b1, unsigned short* __restrict__ x1,
    float* __restrict__ bn_sum, float* __restrict__ bn_ssq, int N) {
  __shared__ unsigned short At[64][328];  // 41 KB; reused as float[64][68] later
  int tid = threadIdx.x;
  int n0 = blockIdx.x * 64;
  int lane = tid & 63, w = tid >> 6;
  int colb = lane & 15, kg = lane >> 4;

  const unsigned short* bp0 = wt2 + (long)(w * 16 + colb) * 320 + kg * 8;
  const unsigned short* bp1 = wt2 + (long)(64 + w * 16 + colb) * 320 + kg * 8;
  const unsigned short* bp2 = wt2 + (long)(128 + w * 16 + colb) * 320 + kg * 8;
  h16x8 bf0[10], bf1[8], bf2[8];
#pragma unroll
  for (int kk = 0; kk < 10; kk++) bf0[kk] = *(const h16x8*)(bp0 + kk * 32);
#pragma unroll
  for (int j = 0; j < 8; j++) bf1[j] = *(const h16x8*)(bp1 + (j + 2) * 32);
#pragma unroll
  for (int j = 0; j < 8; j++) bf2[j] = *(const h16x8*)(bp2 + (j + 2) * 32);

  for (int idx = tid; idx < 64 * 40; idx += 256) {
    int row = idx / 40, s = idx - row * 40;
    int n = n0 + row;
    us8 o = {0, 0, 0, 0, 0, 0, 0, 0};
    if (n < N) {
      if (s < 8) {
        f32x4 v0 = *(const f32x4*)(nf + (long)n * 64 + s * 8);
        f32x4 v1 = *(const f32x4*)(nf + (long)n * 64 + s * 8 + 4);
        o[0] = f2h(v0.x); o[1] = f2h(v0.y); o[2] = f2h(v0.z); o[3] = f2h(v0.w);
        o[4] = f2h(v1.x); o[5] = f2h(v1.y); o[6] = f2h(v1.z); o[7] = f2h(v1.w);
      } else {
        o = *((const us8*)(aggb + (long)n * 256) + (s - 8));
      }
    }
    *(us8*)&At[row][s * 8] = o;
  }
  __syncthreads();

  f32x4 acc0[4], acc1[4], acc2[4];
#pragma unroll
  for (int s = 0; s < 4; s++) {
    acc0[s] = (f32x4){0.f, 0.f, 0.f, 0.f};
    acc1[s] = (f32x4){0.f, 0.f, 0.f, 0.f};
    acc2[s] = (f32x4){0.f, 0.f, 0.f, 0.f};
  }
#pragma unroll
  for (int s = 0; s < 4; s++) {
    const unsigned short* ap = &At[s * 16 + colb][kg * 8];
#pragma unroll
    for (int kk = 0; kk < 10; kk++) {
      h16x8 a = *(const h16x8*)(ap + kk * 32);
      acc0[s] = __builtin_amdgcn_mfma_f32_16x16x32_f16(a, bf0[kk], acc0[s], 0, 0, 0);
      if (kk >= 2) {
        acc1[s] = __builtin_amdgcn_mfma_f32_16x16x32_f16(a, bf1[kk - 2], acc1[s], 0, 0, 0);
        acc2[s] = __builtin_amdgcn_mfma_f32_16x16x32_f16(a, bf2[kk - 2], acc2[s], 0, 0, 0);
      }
    }
  }
  __syncthreads();

  float* sx = (float*)&At[0][0];
  int col = w * 16 + colb;
  float bv = b1[col];
#pragma unroll
  for (int s = 0; s < 4; s++) {
    int rb = s * 16 + kg * 4;
#pragma unroll
    for (int r = 0; r < 4; r++) {
      int n = n0 + rb + r;
      float x = 0.f;
      if (n < N) {
        float lg = aux2[(long)n * 2];
        float atf = aux2[(long)n * 2 + 1];
        x = fmaxf(acc0[s][r] + lg * acc1[s][r] + atf * acc2[s][r] + bv, 0.f);
      }
      sx[(rb + r) * 68 + col] = x;
    }
  }
  __syncthreads();

  for (int idx = tid; idx < 64 * 16; idx += 256) {
    int row = idx >> 4, s4 = idx & 15;
    int n = n0 + row;
    if (n < N) {
      const float* p = sx + row * 68 + s4 * 4;
      us4 o;
      o.x = f2h(p[0]); o.y = f2h(p[1]); o.z = f2h(p[2]); o.w = f2h(p[3]);
      *(us4*)(x1 + (long)n * 64 + s4 * 4) = o;
    }
  }
  if (tid < 64) {
    float s = 0.f, s2 = 0.f;
    for (int r = 0; r < 64; r++) {
      float v = sx[r * 68 + tid];
      s += v;
      s2 = fmaf(v, v, s2);
    }
    atomicAdd(&bn_sum[tid], s);
    atomicAdd(&bn_ssq[tid], s2);
  }
}

// ---------------- BN stats finalize -----------------------------------------

__global__ __launch_bounds__(64) void k_bnstat(
    const float* __restrict__ bn_sum, const float* __restrict__ bn_ssq,
    const float* __restrict__ gamma, const float* __restrict__ beta,
    float* __restrict__ scale, float* __restrict__ shift, float invN) {
  int j = threadIdx.x;
  float mu = bn_sum[j] * invN;
  float v = fmaxf(bn_ssq[j] * invN - mu * mu, 0.f);
  float sc = gamma[j] / sqrtf(v + EPSF);
  scale[j] = sc;
  shift[j] = beta[j] - mu * sc;
}

// ---------------- out = relu(BN(x1)@W2 + b2) + h_in (MFMA tile) --------------

__global__ __launch_bounds__(256) void k_post2(
    const unsigned short* __restrict__ x1, const unsigned short* __restrict__ wt3,
    const float* __restrict__ post_b2, const float* __restrict__ scale,
    const float* __restrict__ shift, const float* __restrict__ nf,
    float* __restrict__ out, int N) {
  __shared__ unsigned short at[64][72];
  int tid = threadIdx.x;
  int n0 = blockIdx.x * 64;
  for (int idx = tid; idx < 64 * 16; idx += 256) {
    int row = idx >> 4, s4 = idx & 15;
    int n = n0 + row;
    us4 o = {0, 0, 0, 0};
    if (n < N) {
      us4 xv = *(const us4*)(x1 + (long)n * 64 + s4 * 4);
      f32x4 sc = *(const f32x4*)(scale + s4 * 4);
      f32x4 sh = *(const f32x4*)(shift + s4 * 4);
      o.x = f2h(fmaf(h2f(xv.x), sc.x, sh.x));
      o.y = f2h(fmaf(h2f(xv.y), sc.y, sh.y));
      o.z = f2h(fmaf(h2f(xv.z), sc.z, sh.z));
      o.w = f2h(fmaf(h2f(xv.w), sc.w, sh.w));
    }
    *(us4*)&at[row][s4 * 4] = o;
  }
  __syncthreads();
  int lane = tid & 63, w = tid >> 6;
  int colb = lane & 15, kg = lane >> 4;
  int r0 = w * 16;
  const unsigned short* ap = &at[r0 + colb][kg * 8];
  const unsigned short* bp = wt3 + colb * 64 + kg * 8;
  f32x4 acc[4];
#pragma unroll
  for (int ct = 0; ct < 4; ct++) acc[ct] = (f32x4){0.f, 0.f, 0.f, 0.f};
#pragma unroll
  for (int kk = 0; kk < 2; kk++) {
    h16x8 a = *(const h16x8*)(ap + kk * 32);
#pragma unroll
    for (int ct = 0; ct < 4; ct++) {
      h16x8 b = *(const h16x8*)(bp + ct * (16 * 64) + kk * 32);
      acc[ct] = __builtin_amdgcn_mfma_f32_16x16x32_f16(a, b, acc[ct], 0, 0, 0);
    }
  }
  int rb = r0 + kg * 4;
#pragma unroll
  for (int ct = 0; ct < 4; ct++) {
    int col = ct * 16 + colb;
    float bv = post_b2[col];
#pragma unroll
    for (int r = 0; r < 4; r++) {
      int n = n0 + rb + r;
      if (n < N)
        out[(long)n * 64 + col] =
            fmaxf(acc[ct][r] + bv, 0.f) + nf[(long)n * 64 + col];
    }
  }
}

// ----------------------------------------------------------------------------

extern "C" void kernel_launch(void* const* d_in, const int* in_sizes, int n_in,
                              void* d_out, int out_size, void* d_ws, size_t ws_size,
                              hipStream_t stream) {
  const float* node_feat = (const float*)d_in[0];
  const float* edge_feat = (const float*)d_in[1];
  const float* pre_W = (const float*)d_in[2];
  const float* pre_b = (const float*)d_in[3];
  const float* post_W1 = (const float*)d_in[4];
  const float* post_b1 = (const float*)d_in[5];
  const float* bn_gamma = (const float*)d_in[6];
  const float* bn_beta = (const float*)d_in[7];
  const float* post_W2 = (const float*)d_in[8];
  const float* post_b2 = (const float*)d_in[9];
  const int* src = (const int*)d_in[10];
  const int* dst = (const int*)d_in[11];
  float* out = (float*)d_out;

  int N = in_sizes[0] / 64;
  int E = in_sizes[10];

  char* ws = (char*)d_ws;
  size_t off = 0;
  auto alloc = [&](size_t bytes) -> void* {
    void* p = ws + off;
    off += (bytes + 255) & ~(size_t)255;
    return p;
  };
  int* deg = (int*)alloc((size_t)N * 4);
  float* bn_sum = (float*)alloc(64 * 4);
  float* bn_ssq = (float*)alloc(64 * 4);
  size_t zero_span = off;
  int* offs = (int*)alloc((size_t)N * 4);
  int* rank = (int*)alloc((size_t)E * 4);
  int* bsum = (int*)alloc(1024 * 4);
  unsigned short* aggb = (unsigned short*)alloc((size_t)N * 256 * 2);
  float* aux2 = (float*)alloc((size_t)N * 2 * 4);
  unsigned short* psb = (unsigned short*)alloc((size_t)N * 64 * 2);
  unsigned short* pdb = (unsigned short*)alloc((size_t)N * 64 * 2);
  unsigned short* x1 = (unsigned short*)alloc((size_t)N * 64 * 2);
  unsigned short* wsdt = (unsigned short*)alloc(128 * 64 * 2);
  unsigned short* wt2 = (unsigned short*)alloc(192 * 320 * 2);
  unsigned short* wt3 = (unsigned short*)alloc(64 * 64 * 2);
  float* bn_scale = (float*)alloc(64 * 4);
  float* bn_shift = (float*)alloc(64 * 4);
  unsigned short* rbuf = (unsigned short*)alloc((size_t)E * 64 * 2);
  if (off > ws_size) return;  // fail loudly (output stays poisoned)

  int nscan = (N + 1023) / 1024;
  int degBlocks = (E + 255) / 256;
  int prepBlocks = (128 * 64 + 192 * 320 + 64 * 64 + 255) / 256;

  hipMemsetAsync(deg, 0, zero_span, stream);
  k_front<<<degBlocks + prepBlocks, 256, 0, stream>>>(
      dst, deg, rank, E, degBlocks, pre_W, post_W1, post_W2, wsdt, wt2, wt3);
  k_scan_a<<<nscan, 1024, 0, stream>>>(deg, offs, bsum, aux2, N);
  k_scan_b<<<1, 1024, 0, stream>>>(bsum, nscan);
  kB_proj<<<(N + 63) / 64, 256, 0, stream>>>(node_feat, wsdt, pre_b, psb, pdb, N);

  kQe<<<(E + 511) / 512, 256, 0, stream>>>(edge_feat, pre_W, psb, src, dst,
                                           rank, offs, bsum, rbuf, E);
  kAgg<<<(N + 3) / 4, 256, 0, stream>>>(rbuf, pdb, offs, bsum, deg, aggb, N);

  kC_post1<<<(N + 63) / 64, 256, 0, stream>>>(node_feat, aggb, aux2, wt2,
                                              post_b1, x1, bn_sum, bn_ssq, N);

  k_bnstat<<<1, 64, 0, stream>>>(bn_sum, bn_ssq, bn_gamma, bn_beta, bn_scale,
                                 bn_shift, 1.0f / (float)N);

  k_post2<<<(N + 63) / 64, 256, 0, stream>>>(x1, wt3, post_b2, bn_scale,
                                             bn_shift, node_feat, out, N);
}